// Round 1
// baseline (538.300 us; speedup 1.0000x reference)
//
#include <hip/hip_runtime.h>
#include <hip/hip_bf16.h>
#include <math.h>

// ---------------------------------------------------------------------------
// ChunkGatedAttentionUnit: B=2, S=4096, H=1024, D=2048, CHUNK=128, nC=32
//
// Pipeline (all bf16 MFMA, f32 accumulate):
//   1. convert hs -> bf16; transpose+convert W{q,k,v,g} -> Wt [D][H], Wo -> Wot [H][D]
//   2. QKVG = hs @ W + b (sigmoid for G) -> bf16 [4][8192][2048]
//   3. V -> Vt [B][D][S] (transpose for PV GEMM B-operand)
//   4. pair kernel: P_ij = Q_i K_j^T for j<=i  (diag: *scale, causal mask)
//   5. softmax on diagonal blocks (rowwise, within-chunk)
//   6. OutPre = (P_i @ V[0:Li]) * gate   (local+cross fused, gate fused)
//   7. out = OutPre @ Wo + bo  (f32 output)
//
// Inter-chunk scan replaced by equivalent block-lower-triangular pairwise form
// (same FLOPs, fully parallel).
// ---------------------------------------------------------------------------

typedef __bf16 bf16_t;
typedef __bf16 bf16x8 __attribute__((ext_vector_type(8)));
typedef __bf16 bf16x4 __attribute__((ext_vector_type(4)));
typedef float f32x4 __attribute__((ext_vector_type(4)));

#define NB 2
#define SEQ 4096
#define HID 1024
#define DD 2048
#define CS 128
#define NC 32
#define BS 8192            // NB*SEQ
#define PB 8650752l        // per-batch P elems: 128*128*528

__device__ __forceinline__ void async16(const void* g, void* l) {
  __builtin_amdgcn_global_load_lds(
      (const __attribute__((address_space(1))) void*)g,
      (__attribute__((address_space(3))) void*)l, 16, 0, 0);
}

// 128x128 output tile, BK=64, 256 threads (4 waves in 2x2), MFMA 16x16x32 bf16.
// A: row-major [>=128, K] stride lda. B: row-major Bt [>=128, K] stride ldb
// (i.e. C = A @ Bt^T).  m97 structure: global_load_lds(16B) -> 2 barriers/K-step.
__device__ __forceinline__ void gemm_tile(
    const bf16_t* __restrict__ A, int lda,
    const bf16_t* __restrict__ B, int ldb,
    int K, bf16_t* lsA, bf16_t* lsB, f32x4 acc[4][4]) {
  const int t = threadIdx.x;
  const int lane = t & 63, w = t >> 6;
  const int wr = w >> 1, wc = w & 1;
  const int lg = lane >> 4, lr = lane & 15;

  f32x4 zero = {0.f, 0.f, 0.f, 0.f};
#pragma unroll
  for (int m = 0; m < 4; ++m)
#pragma unroll
    for (int n = 0; n < 4; ++n) acc[m][n] = zero;

  const int e0 = t * 8;
  for (int k0 = 0; k0 < K; k0 += 64) {
#pragma unroll
    for (int c = 0; c < 4; ++c) {
      int e = c * 2048 + e0;
      int r = e >> 6, cc = e & 63;
      async16(A + (long)r * lda + (k0 + cc), lsA + e);
      async16(B + (long)r * ldb + (k0 + cc), lsB + e);
    }
    __syncthreads();  // compiler emits vmcnt(0) drain before s_barrier
#pragma unroll
    for (int kk = 0; kk < 64; kk += 32) {
      bf16x8 af[4], bfr[4];
#pragma unroll
      for (int m = 0; m < 4; ++m)
        af[m] = *reinterpret_cast<const bf16x8*>(
            &lsA[(wr * 64 + m * 16 + lr) * 64 + kk + lg * 8]);
#pragma unroll
      for (int n = 0; n < 4; ++n)
        bfr[n] = *reinterpret_cast<const bf16x8*>(
            &lsB[(wc * 64 + n * 16 + lr) * 64 + kk + lg * 8]);
#pragma unroll
      for (int m = 0; m < 4; ++m)
#pragma unroll
        for (int n = 0; n < 4; ++n)
          acc[m][n] =
              __builtin_amdgcn_mfma_f32_16x16x32_bf16(af[m], bfr[n], acc[m][n], 0, 0, 0);
    }
    __syncthreads();
  }
}

// --- elementwise convert f32 -> bf16 (vectorized) ---------------------------
__global__ void k_cvt(const float4* __restrict__ in, bf16x4* __restrict__ out, int n4) {
  int i = blockIdx.x * blockDim.x + threadIdx.x;
  if (i < n4) {
    float4 v = in[i];
    bf16x4 o;
    o[0] = (bf16_t)v.x; o[1] = (bf16_t)v.y; o[2] = (bf16_t)v.z; o[3] = (bf16_t)v.w;
    out[i] = o;
  }
}

// --- tiled transpose + convert f32[R][C] -> bf16[C][R] ----------------------
__global__ void k_tconv(const float* __restrict__ in, bf16_t* __restrict__ out,
                        int R, int C) {
  __shared__ bf16_t tile[64][65];
  int bc = blockIdx.x, br = blockIdx.y;
  int t = threadIdx.x;
  int c = t & 63, r0 = t >> 6;
#pragma unroll
  for (int rr = 0; rr < 64; rr += 4) {
    int r = rr + r0;
    tile[r][c] = (bf16_t)in[(long)(br * 64 + r) * C + bc * 64 + c];
  }
  __syncthreads();
#pragma unroll
  for (int rr = 0; rr < 64; rr += 4) {
    int r = rr + r0;
    out[(long)(bc * 64 + r) * R + br * 64 + c] = tile[c][r];
  }
}

// --- tiled transpose bf16[R][C] -> bf16[C][R], per batch (z) ----------------
__global__ void k_tbf16(const bf16_t* __restrict__ in, bf16_t* __restrict__ out,
                        int R, int C) {
  __shared__ bf16_t tile[64][65];
  long zoff = (long)blockIdx.z * R * C;
  in += zoff;
  out += zoff;
  int bc = blockIdx.x, br = blockIdx.y;
  int t = threadIdx.x;
  int c = t & 63, r0 = t >> 6;
#pragma unroll
  for (int rr = 0; rr < 64; rr += 4) {
    int r = rr + r0;
    tile[r][c] = in[(long)(br * 64 + r) * C + bc * 64 + c];
  }
  __syncthreads();
#pragma unroll
  for (int rr = 0; rr < 64; rr += 4) {
    int r = rr + r0;
    out[(long)(bc * 64 + r) * R + br * 64 + c] = tile[c][r];
  }
}

// --- GEMM1: QKVG = hsb @ Wt^T + bias (sigmoid on z==3) ----------------------
__global__ void k_gemm_qkvg(const bf16_t* __restrict__ hsb,
                            const bf16_t* __restrict__ Wt4,
                            const float* __restrict__ bq, const float* __restrict__ bk,
                            const float* __restrict__ bv, const float* __restrict__ bg,
                            bf16_t* __restrict__ out) {
  __shared__ bf16_t lsA[128 * 64], lsB[128 * 64];
  const int nb = blockIdx.x, mb = blockIdx.y, z = blockIdx.z;
  const bf16_t* A = hsb + (long)mb * 128 * HID;
  const bf16_t* B = Wt4 + (long)z * DD * HID + (long)nb * 128 * HID;
  f32x4 acc[4][4];
  gemm_tile(A, HID, B, HID, HID, lsA, lsB, acc);

  const float* bias = (z == 0) ? bq : (z == 1) ? bk : (z == 2) ? bv : bg;
  bf16_t* O = out + (long)z * BS * DD;
  const int t = threadIdx.x;
  const int lane = t & 63, w = t >> 6;
  const int wr = w >> 1, wc = w & 1, lg = lane >> 4, lr = lane & 15;
#pragma unroll
  for (int m = 0; m < 4; ++m)
#pragma unroll
    for (int reg = 0; reg < 4; ++reg) {
      int row = mb * 128 + wr * 64 + m * 16 + lg * 4 + reg;
#pragma unroll
      for (int n = 0; n < 4; ++n) {
        int col = nb * 128 + wc * 64 + n * 16 + lr;
        float v = acc[m][n][reg] + bias[col];
        if (z == 3) v = 1.f / (1.f + __expf(-v));
        O[(long)row * DD + col] = (bf16_t)v;
      }
    }
}

// --- pair kernel: P_ij = Q_i K_j^T (j<=i); diag: *scale + causal mask -------
__global__ void k_pair(const bf16_t* __restrict__ Q, const bf16_t* __restrict__ Kb,
                       bf16_t* __restrict__ Pout) {
  __shared__ bf16_t lsA[128 * 64], lsB[128 * 64];
  int p = blockIdx.x, b = blockIdx.y;
  int i = 0, base = 0;
  while (base + i + 1 <= p) { base += i + 1; ++i; }
  int j = p - base;

  const bf16_t* A = Q + ((long)b * SEQ + (long)i * CS) * DD;
  const bf16_t* B = Kb + ((long)b * SEQ + (long)j * CS) * DD;
  f32x4 acc[4][4];
  gemm_tile(A, DD, B, DD, DD, lsA, lsB, acc);

  long Li = (long)(i + 1) * CS;
  bf16_t* Pp = Pout + (long)b * PB + 16384l * ((long)i * (i + 1) / 2) + (long)j * CS;
  const float scale = 0.02209708691207961f;  // 1/sqrt(2048)
  const int t = threadIdx.x;
  const int lane = t & 63, w = t >> 6;
  const int wr = w >> 1, wc = w & 1, lg = lane >> 4, lr = lane & 15;
#pragma unroll
  for (int m = 0; m < 4; ++m)
#pragma unroll
    for (int reg = 0; reg < 4; ++reg) {
      int row = wr * 64 + m * 16 + lg * 4 + reg;
#pragma unroll
      for (int n = 0; n < 4; ++n) {
        int col = wc * 64 + n * 16 + lr;
        float v = acc[m][n][reg];
        if (i == j) {
          v *= scale;
          if (col > row) v = -INFINITY;
        }
        Pp[(long)row * Li + col] = (bf16_t)v;
      }
    }
}

// --- rowwise softmax on diagonal P blocks (causal within chunk) -------------
__global__ void k_softmax_diag(bf16_t* __restrict__ P) {
  int cg = blockIdx.x;
  int b = cg >> 5, i = cg & 31;
  long Li = (long)(i + 1) * CS;
  int r = threadIdx.x;  // 128 threads, one row each
  bf16_t* row = P + (long)b * PB + 16384l * ((long)i * (i + 1) / 2) + (long)i * CS +
                (long)r * Li;
  float mx = -INFINITY;
  for (int c = 0; c <= r; ++c) mx = fmaxf(mx, (float)row[c]);
  float s = 0.f;
  for (int c = 0; c <= r; ++c) s += __expf((float)row[c] - mx);
  float inv = 1.f / s;
  for (int c = 0; c < 128; ++c) {
    float v = (c <= r) ? __expf((float)row[c] - mx) * inv : 0.f;
    row[c] = (bf16_t)v;
  }
}

// --- GEMM2: OutPre = (P_i @ V[0:Li]) * gate  --------------------------------
__global__ void k_gemm2(const bf16_t* __restrict__ P, const bf16_t* __restrict__ Vt,
                        const bf16_t* __restrict__ G, bf16_t* __restrict__ OutPre) {
  __shared__ bf16_t lsA[128 * 64], lsB[128 * 64];
  int nb = blockIdx.x, cg = blockIdx.y;
  int b = cg >> 5, i = cg & 31;
  int Li = (i + 1) * CS;
  const bf16_t* A = P + (long)b * PB + 16384l * ((long)i * (i + 1) / 2);
  const bf16_t* B = Vt + (long)b * DD * SEQ + (long)nb * 128 * SEQ;
  f32x4 acc[4][4];
  gemm_tile(A, Li, B, SEQ, Li, lsA, lsB, acc);

  const int t = threadIdx.x;
  const int lane = t & 63, w = t >> 6;
  const int wr = w >> 1, wc = w & 1, lg = lane >> 4, lr = lane & 15;
#pragma unroll
  for (int m = 0; m < 4; ++m)
#pragma unroll
    for (int reg = 0; reg < 4; ++reg) {
      int row = wr * 64 + m * 16 + lg * 4 + reg;
      long srow = (long)b * SEQ + (long)i * CS + row;
#pragma unroll
      for (int n = 0; n < 4; ++n) {
        int col = nb * 128 + wc * 64 + n * 16 + lr;
        long idx = srow * DD + col;
        float g = (float)G[idx];
        OutPre[idx] = (bf16_t)(acc[m][n][reg] * g);
      }
    }
}

// --- GEMM3: out = OutPre @ Wo + bo (f32 out) --------------------------------
__global__ void k_gemm3(const bf16_t* __restrict__ OutPre, const bf16_t* __restrict__ Wot,
                        const float* __restrict__ bo, float* __restrict__ out) {
  __shared__ bf16_t lsA[128 * 64], lsB[128 * 64];
  int nb = blockIdx.x, mb = blockIdx.y;
  const bf16_t* A = OutPre + (long)mb * 128 * DD;
  const bf16_t* B = Wot + (long)nb * 128 * DD;
  f32x4 acc[4][4];
  gemm_tile(A, DD, B, DD, DD, lsA, lsB, acc);

  const int t = threadIdx.x;
  const int lane = t & 63, w = t >> 6;
  const int wr = w >> 1, wc = w & 1, lg = lane >> 4, lr = lane & 15;
#pragma unroll
  for (int m = 0; m < 4; ++m)
#pragma unroll
    for (int reg = 0; reg < 4; ++reg) {
      int row = mb * 128 + wr * 64 + m * 16 + lg * 4 + reg;
#pragma unroll
      for (int n = 0; n < 4; ++n) {
        int col = nb * 128 + wc * 64 + n * 16 + lr;
        out[(long)row * HID + col] = acc[m][n][reg] + bo[col];
      }
    }
}

extern "C" void kernel_launch(void* const* d_in, const int* in_sizes, int n_in,
                              void* d_out, int out_size, void* d_ws, size_t ws_size,
                              hipStream_t stream) {
  const float* hs = (const float*)d_in[0];
  const float* Wq = (const float*)d_in[1];
  const float* bq = (const float*)d_in[2];
  const float* Wk = (const float*)d_in[3];
  const float* bk = (const float*)d_in[4];
  const float* Wv = (const float*)d_in[5];
  const float* bv = (const float*)d_in[6];
  const float* Wg = (const float*)d_in[7];
  const float* bg = (const float*)d_in[8];
  const float* Wo = (const float*)d_in[9];
  const float* bo = (const float*)d_in[10];
  float* out = (float*)d_out;

  char* ws = (char*)d_ws;
  size_t off = 0;
  auto alloc = [&](size_t bytes) {
    void* p = ws + off;
    off += (bytes + 255) & ~(size_t)255;
    return p;
  };
  bf16_t* hsb = (bf16_t*)alloc((size_t)BS * HID * 2);          // 16 MB
  bf16_t* Wt4 = (bf16_t*)alloc((size_t)4 * DD * HID * 2);      // 16 MB
  bf16_t* Wot = (bf16_t*)alloc((size_t)HID * DD * 2);          // 4 MB
  bf16_t* QKVG = (bf16_t*)alloc((size_t)4 * BS * DD * 2);      // 128 MB
  bf16_t* Vt = (bf16_t*)alloc((size_t)NB * DD * SEQ * 2);      // 32 MB
  bf16_t* P = (bf16_t*)alloc((size_t)NB * PB * 2);             // 33 MB

  bf16_t* Qb = QKVG;
  bf16_t* Kbuf = QKVG + (long)BS * DD;
  bf16_t* Vbuf = QKVG + 2l * BS * DD;
  bf16_t* Gbuf = QKVG + 3l * BS * DD;
  bf16_t* OutPre = Vbuf;  // alias: V row-major dead after Vt built

  // 1. conversions
  k_cvt<<<(BS * HID / 4 + 255) / 256, 256, 0, stream>>>((const float4*)hs,
                                                        (bf16x4*)hsb, BS * HID / 4);
  k_tconv<<<dim3(DD / 64, HID / 64), 256, 0, stream>>>(Wq, Wt4 + 0l * DD * HID, HID, DD);
  k_tconv<<<dim3(DD / 64, HID / 64), 256, 0, stream>>>(Wk, Wt4 + 1l * DD * HID, HID, DD);
  k_tconv<<<dim3(DD / 64, HID / 64), 256, 0, stream>>>(Wv, Wt4 + 2l * DD * HID, HID, DD);
  k_tconv<<<dim3(DD / 64, HID / 64), 256, 0, stream>>>(Wg, Wt4 + 3l * DD * HID, HID, DD);
  k_tconv<<<dim3(HID / 64, DD / 64), 256, 0, stream>>>(Wo, Wot, DD, HID);

  // 2. QKVG projection
  k_gemm_qkvg<<<dim3(DD / 128, BS / 128, 4), 256, 0, stream>>>(hsb, Wt4, bq, bk, bv, bg,
                                                               QKVG);

  // 3. V -> Vt
  k_tbf16<<<dim3(DD / 64, SEQ / 64, NB), 256, 0, stream>>>(Vbuf, Vt, SEQ, DD);

  // 4. pairwise scores
  k_pair<<<dim3(NC * (NC + 1) / 2, NB), 256, 0, stream>>>(Qb, Kbuf, P);

  // 5. diagonal softmax
  k_softmax_diag<<<NB * NC, 128, 0, stream>>>(P);

  // 6. PV + gate
  k_gemm2<<<dim3(DD / 128, NB * NC), 256, 0, stream>>>(P, Vt, Gbuf, OutPre);

  // 7. output projection
  k_gemm3<<<dim3(HID / 128, BS / 128), 256, 0, stream>>>(OutPre, Wot, bo, out);
}

// Round 2
// 485.614 us; speedup vs baseline: 1.1085x; 1.1085x over previous
//
#include <hip/hip_runtime.h>
#include <hip/hip_bf16.h>
#include <math.h>

// ---------------------------------------------------------------------------
// ChunkGatedAttentionUnit: B=2, S=4096, H=1024, D=2048, CHUNK=128, nC=32
// Round 2: 256x256 8-wave GEMM core (T2 swizzle + T3/T4 counted vmcnt + T5
// setprio), rectangular P, softmax fused into pair epilogue.
// ---------------------------------------------------------------------------

typedef __bf16 bf16_t;
typedef __bf16 bf16x8 __attribute__((ext_vector_type(8)));
typedef __bf16 bf16x4 __attribute__((ext_vector_type(4)));
typedef float f32x4 __attribute__((ext_vector_type(4)));

#define NB_ 2
#define SEQ 4096
#define HID 1024
#define DD 2048
#define NCH 32
#define BS 8192
#define LDS_BYTES 131072

__device__ __forceinline__ void async16(const void* g, void* l) {
  __builtin_amdgcn_global_load_lds(
      (const __attribute__((address_space(1))) void*)g,
      (__attribute__((address_space(3))) void*)l, 16, 0, 0);
}

#define VMW4 asm volatile("s_waitcnt vmcnt(4)" ::: "memory")
#define VMW0 asm volatile("s_waitcnt vmcnt(0)" ::: "memory")
#define FEN asm volatile("" ::: "memory")
#define BARR __builtin_amdgcn_s_barrier()

template <int MFH>
__device__ __forceinline__ void readA8(const bf16_t* bufA, int aBase, int s0, int s1,
                                       bf16x8 (&af)[4][2]) {
#pragma unroll
  for (int mm = 0; mm < 4; ++mm) {
    int p = aBase + MFH * 8192 + mm * 1024;
    af[mm][0] = *reinterpret_cast<const bf16x8*>(&bufA[p + s0]);
    af[mm][1] = *reinterpret_cast<const bf16x8*>(&bufA[p + s1]);
  }
}
template <int NFH>
__device__ __forceinline__ void readB4(const bf16_t* bufB, int bBase, int s0, int s1,
                                       bf16x8 (&bv)[2][2]) {
#pragma unroll
  for (int nn = 0; nn < 2; ++nn) {
    int p = bBase + NFH * 8192 + nn * 1024;
    bv[nn][0] = *reinterpret_cast<const bf16x8*>(&bufB[p + s0]);
    bv[nn][1] = *reinterpret_cast<const bf16x8*>(&bufB[p + s1]);
  }
}
template <int MFH, int NFH>
__device__ __forceinline__ void mfma16(const bf16x8 (&af)[4][2], const bf16x8 (&bv)[2][2],
                                       f32x4 (&acc)[8][4]) {
  __builtin_amdgcn_s_setprio(1);
#pragma unroll
  for (int kki = 0; kki < 2; ++kki)
#pragma unroll
    for (int mm = 0; mm < 4; ++mm)
#pragma unroll
      for (int nn = 0; nn < 2; ++nn)
        acc[MFH * 4 + mm][NFH * 2 + nn] = __builtin_amdgcn_mfma_f32_16x16x32_bf16(
            af[mm][kki], bv[nn][kki], acc[MFH * 4 + mm][NFH * 2 + nn], 0, 0, 0);
  __builtin_amdgcn_s_setprio(0);
}

// C = A[256,K] @ B[256,K]^T. LDS layout per operand tile: permuted rows
// (wave-major) + XOR-16B swizzle; inverse permutation/swizzle folded into
// per-lane global source address so global_load_lds dest stays linear.
__device__ __forceinline__ void gemm256(const bf16_t* __restrict__ A, int lda,
                                        const bf16_t* __restrict__ B, int ldb, int nt,
                                        bf16_t* lds, f32x4 (&acc)[8][4]) {
  const int t = threadIdx.x;
  const int lane = t & 63, w = t >> 6;
  const int wm = w >> 2, wn = w & 3;
  const int lr = lane & 15, lg = lane >> 4;
  const int xm = lr & 7;

  const int aBase = (wm * 64 + lr) * 64;
  const int bBase = (wn * 32 + lr) * 64;
  const int s0 = (lg ^ xm) * 8;
  const int s1 = ((4 + lg) ^ xm) * 8;

  int srcA[4], srcB[4];
  const int slog = ((t & 7) ^ ((t >> 3) & 7)) * 8;
#pragma unroll
  for (int blk = 0; blk < 4; ++blk) {
    // A permuted row pr = blk*64 + (t>>3): mfh=blk>>1, wm=blk&1 -> logical row
    int rA = ((blk & 1) << 7) + ((blk >> 1) << 6) + (t >> 3);
    // B permuted row: nfh=pr>>7, wn=(pr>>5)&3, rem=pr&31 -> logical row
    int prB = (blk << 6) + (t >> 3);
    int rB = (((prB >> 5) & 3) << 6) + ((prB >> 7) << 5) + (prB & 31);
    srcA[blk] = rA * lda + slog;
    srcB[blk] = rB * ldb + slog;
  }
  const int dstT = t * 8;

#pragma unroll
  for (int m = 0; m < 8; ++m)
#pragma unroll
    for (int n = 0; n < 4; ++n) acc[m][n] = (f32x4){0.f, 0.f, 0.f, 0.f};

  {  // prologue: stage tile 0 into buf0, order A0,A1,B0,B1,A2,A3,B2,B3
    bf16_t* nA = lds;
    bf16_t* nB = lds + 16384;
    async16(A + srcA[0], nA + dstT);
    async16(A + srcA[1], nA + 4096 + dstT);
    async16(B + srcB[0], nB + dstT);
    async16(B + srcB[1], nB + 4096 + dstT);
    async16(A + srcA[2], nA + 8192 + dstT);
    async16(A + srcA[3], nA + 12288 + dstT);
    async16(B + srcB[2], nB + 8192 + dstT);
    async16(B + srcB[3], nB + 12288 + dstT);
  }

  bf16x8 af0[4][2], af1[4][2], bv0[2][2], bv1[2][2];

  for (int kt = 0; kt < nt; ++kt) {
    bf16_t* bufA = lds + ((kt & 1) << 15);
    bf16_t* bufB = bufA + 16384;
    bf16_t* nA = lds + (((kt + 1) & 1) << 15);
    bf16_t* nB = nA + 16384;
    const int kn = (kt + 1 < nt ? (kt + 1) : 0) << 6;
    const bf16_t* An = A + kn;
    const bf16_t* Bn = B + kn;
    // q0: (mfh0,nfh0) — needs A0,A1,B0,B1 of tile kt
    VMW4; BARR; FEN;
    readA8<0>(bufA, aBase, s0, s1, af0);
    readB4<0>(bufB, bBase, s0, s1, bv0);
    mfma16<0, 0>(af0, bv0, acc);
    async16(An + srcA[0], nA + dstT);
    async16(An + srcA[1], nA + 4096 + dstT);
    // q1: (mfh1,nfh0) — needs A2,A3
    VMW4; BARR; FEN;
    readA8<1>(bufA, aBase, s0, s1, af1);
    mfma16<1, 0>(af1, bv0, acc);
    async16(Bn + srcB[0], nB + dstT);
    async16(Bn + srcB[1], nB + 4096 + dstT);
    // q2: (mfh1,nfh1) — needs B2,B3
    VMW4; BARR; FEN;
    readB4<1>(bufB, bBase, s0, s1, bv1);
    mfma16<1, 1>(af1, bv1, acc);
    async16(An + srcA[2], nA + 8192 + dstT);
    async16(An + srcA[3], nA + 12288 + dstT);
    // q3: (mfh0,nfh1) — re-reads A0,A1 (landed since q0; no wait needed)
    readA8<0>(bufA, aBase, s0, s1, af0);
    mfma16<0, 1>(af0, bv1, acc);
    async16(Bn + srcB[2], nB + 8192 + dstT);
    async16(Bn + srcB[3], nB + 12288 + dstT);
  }
  VMW0;  // quiesce LDS so epilogues may reuse it
  BARR;
}

// --- elementwise convert f32 -> bf16 ---------------------------------------
__global__ void k_cvt(const float4* __restrict__ in, bf16x4* __restrict__ out, int n4) {
  int i = blockIdx.x * blockDim.x + threadIdx.x;
  if (i < n4) {
    float4 v = in[i];
    bf16x4 o;
    o[0] = (bf16_t)v.x; o[1] = (bf16_t)v.y; o[2] = (bf16_t)v.z; o[3] = (bf16_t)v.w;
    out[i] = o;
  }
}

// --- tiled transpose + convert f32[R][C] -> bf16[C][R] ----------------------
__global__ void k_tconv(const float* __restrict__ in, bf16_t* __restrict__ out,
                        int R, int C) {
  __shared__ bf16_t tile[64][65];
  int bc = blockIdx.x, br = blockIdx.y;
  int t = threadIdx.x;
  int c = t & 63, r0 = t >> 6;
#pragma unroll
  for (int rr = 0; rr < 64; rr += 4) {
    int r = rr + r0;
    tile[r][c] = (bf16_t)in[(long)(br * 64 + r) * C + bc * 64 + c];
  }
  __syncthreads();
#pragma unroll
  for (int rr = 0; rr < 64; rr += 4) {
    int r = rr + r0;
    out[(long)(bc * 64 + r) * R + br * 64 + c] = tile[c][r];
  }
}

// --- tiled transpose bf16[R][C] -> bf16[C][R], per batch (z) ----------------
__global__ void k_tbf16(const bf16_t* __restrict__ in, bf16_t* __restrict__ out,
                        int R, int C) {
  __shared__ bf16_t tile[64][65];
  long zoff = (long)blockIdx.z * R * C;
  in += zoff;
  out += zoff;
  int bc = blockIdx.x, br = blockIdx.y;
  int t = threadIdx.x;
  int c = t & 63, r0 = t >> 6;
#pragma unroll
  for (int rr = 0; rr < 64; rr += 4) {
    int r = rr + r0;
    tile[r][c] = in[(long)(br * 64 + r) * C + bc * 64 + c];
  }
  __syncthreads();
#pragma unroll
  for (int rr = 0; rr < 64; rr += 4) {
    int r = rr + r0;
    out[(long)(bc * 64 + r) * R + br * 64 + c] = tile[c][r];
  }
}

// --- GEMM1: QKVG = hsb @ Wt^T + bias (sigmoid z==3) -------------------------
__global__ __launch_bounds__(512) void k_gemm_qkvg(
    const bf16_t* __restrict__ hsb, const bf16_t* __restrict__ Wt4,
    const float* __restrict__ bq, const float* __restrict__ bk,
    const float* __restrict__ bv, const float* __restrict__ bg,
    bf16_t* __restrict__ out) {
  extern __shared__ bf16_t lds[];
  int c = blockIdx.x;
  int c2 = (c & 7) * 128 + (c >> 3);  // XCD swizzle (1024 % 8 == 0)
  int mb = c2 >> 5, nb = c2 & 31;
  f32x4 acc[8][4];
  gemm256(hsb + (long)mb * 256 * HID, HID, Wt4 + (long)nb * 256 * HID, HID,
          HID / 64, lds, acc);
  const int t = threadIdx.x, lane = t & 63, w = t >> 6;
  const int wm = w >> 2, wn = w & 3, lr = lane & 15, lg = lane >> 4;
  int z = nb >> 3;
  const float* bias = z == 0 ? bq : z == 1 ? bk : z == 2 ? bv : bg;
  int colbase = (nb & 7) * 256 + wn * 64;
  float b4[4];
#pragma unroll
  for (int nf = 0; nf < 4; ++nf) b4[nf] = bias[colbase + nf * 16 + lr];
  bf16_t* O = out + (long)z * BS * DD;
#pragma unroll
  for (int mf = 0; mf < 8; ++mf)
#pragma unroll
    for (int reg = 0; reg < 4; ++reg) {
      long row = mb * 256 + wm * 128 + mf * 16 + lg * 4 + reg;
#pragma unroll
      for (int nf = 0; nf < 4; ++nf) {
        float v = acc[mf][nf][reg] + b4[nf];
        if (z == 3) v = 1.f / (1.f + __expf(-v));
        O[row * DD + colbase + nf * 16 + lr] = (bf16_t)v;
      }
    }
}

// --- pair: P[mpair rows][jt cols] = Q K^T; diag tiles get fused softmax -----
__global__ __launch_bounds__(512) void k_pair(const bf16_t* __restrict__ Q,
                                              const bf16_t* __restrict__ Kb,
                                              bf16_t* __restrict__ P) {
  extern __shared__ bf16_t lds[];
  int p = blockIdx.x, b = blockIdx.y;
  int m = 0, base = 0;
  while (base + m + 1 <= p) { base += m + 1; ++m; }
  int jt = p - base;
  f32x4 acc[8][4];
  gemm256(Q + ((long)b * SEQ + m * 256) * DD, DD,
          Kb + ((long)b * SEQ + jt * 256) * DD, DD, DD / 64, lds, acc);
  const int t = threadIdx.x, lane = t & 63, w = t >> 6;
  const int wm = w >> 2, wn = w & 3, lr = lane & 15, lg = lane >> 4;
  bf16_t* Pt = P + ((long)b * SEQ + m * 256) * (long)SEQ + jt * 256;
  if (jt < m) {  // pure off-diagonal tile: raw scores
#pragma unroll
    for (int mf = 0; mf < 8; ++mf)
#pragma unroll
      for (int reg = 0; reg < 4; ++reg) {
        int row = wm * 128 + mf * 16 + lg * 4 + reg;
#pragma unroll
        for (int nf = 0; nf < 4; ++nf)
          Pt[(long)row * SEQ + wn * 64 + nf * 16 + lr] = (bf16_t)acc[mf][nf][reg];
      }
    return;
  }
  // diagonal tile (jt==m): sub-blocks by chunk: (1,0)=raw, (0,1)=zero,
  // (0,0)&(1,1)=softmax'd diag (scale + causal within chunk).
  const float scale = 0.02209708691207961f;  // 1/sqrt(2048)
  if (wm == 1 && wn < 2) {
#pragma unroll
    for (int mf = 0; mf < 8; ++mf)
#pragma unroll
      for (int reg = 0; reg < 4; ++reg) {
        int row = 128 + mf * 16 + lg * 4 + reg;
#pragma unroll
        for (int nf = 0; nf < 4; ++nf)
          Pt[(long)row * SEQ + wn * 64 + nf * 16 + lr] = (bf16_t)acc[mf][nf][reg];
      }
  }
  if (wm == 0 && wn >= 2) {
#pragma unroll
    for (int mf = 0; mf < 8; ++mf)
#pragma unroll
      for (int reg = 0; reg < 4; ++reg) {
        int row = mf * 16 + lg * 4 + reg;
#pragma unroll
        for (int nf = 0; nf < 4; ++nf)
          Pt[(long)row * SEQ + wn * 64 + nf * 16 + lr] = (bf16_t)0.f;
      }
  }
  float* smf = (float*)lds;  // 64KB scratch (gemm256 quiesced LDS)
#pragma unroll
  for (int h = 0; h < 2; ++h) {
    __syncthreads();
    if (wm == h && (wn >> 1) == h) {
#pragma unroll
      for (int mf = 0; mf < 8; ++mf)
#pragma unroll
        for (int reg = 0; reg < 4; ++reg) {
          int r = mf * 16 + lg * 4 + reg;
#pragma unroll
          for (int nf = 0; nf < 4; ++nf) {
            int cc = (wn & 1) * 64 + nf * 16 + lr;
            float v = acc[mf][nf][reg] * scale;
            smf[r * 128 + ((cc + r) & 127)] = (cc <= r) ? v : -1e30f;  // rotate: bank-spread
          }
        }
    }
    __syncthreads();
    if (t < 128) {
      int r = t;
      float mx = -1e30f;
      for (int cc = 0; cc <= r; ++cc) mx = fmaxf(mx, smf[r * 128 + ((cc + r) & 127)]);
      float s = 0.f;
      for (int cc = 0; cc <= r; ++cc) s += __expf(smf[r * 128 + ((cc + r) & 127)] - mx);
      float inv = 1.f / s;
      for (int cc = 0; cc < 128; ++cc) {
        float v = (cc <= r) ? __expf(smf[r * 128 + ((cc + r) & 127)] - mx) * inv : 0.f;
        Pt[(long)(h * 128 + r) * SEQ + h * 128 + cc] = (bf16_t)v;
      }
    }
  }
}

// --- GEMM2: OutPre = (P @ V[0:K]) * gate ------------------------------------
__global__ __launch_bounds__(512) void k_gemm2(const bf16_t* __restrict__ P,
                                               const bf16_t* __restrict__ Vt,
                                               const bf16_t* __restrict__ G,
                                               bf16_t* __restrict__ OutPre) {
  extern __shared__ bf16_t lds[];
  int nb = blockIdx.x;
  int y = blockIdx.y;
  int b = y >> 4, m = y & 15;
  f32x4 acc[8][4];
  gemm256(P + ((long)b * SEQ + m * 256) * (long)SEQ, SEQ,
          Vt + (long)b * DD * SEQ + (long)nb * 256 * SEQ, SEQ, (m + 1) * 4, lds, acc);
  const int t = threadIdx.x, lane = t & 63, w = t >> 6;
  const int wm = w >> 2, wn = w & 3, lr = lane & 15, lg = lane >> 4;
#pragma unroll
  for (int mf = 0; mf < 8; ++mf)
#pragma unroll
    for (int reg = 0; reg < 4; ++reg) {
      long row = (long)b * SEQ + m * 256 + wm * 128 + mf * 16 + lg * 4 + reg;
#pragma unroll
      for (int nf = 0; nf < 4; ++nf) {
        long idx = row * DD + nb * 256 + wn * 64 + nf * 16 + lr;
        float g = (float)G[idx];
        OutPre[idx] = (bf16_t)(acc[mf][nf][reg] * g);
      }
    }
}

// --- GEMM3: out = OutPre @ Wo + bo (f32 out) --------------------------------
__global__ __launch_bounds__(512) void k_gemm3(const bf16_t* __restrict__ OutPre,
                                               const bf16_t* __restrict__ Wot,
                                               const float* __restrict__ bo,
                                               float* __restrict__ out) {
  extern __shared__ bf16_t lds[];
  int c = blockIdx.x;
  int mb = c >> 2, nb = c & 3;
  f32x4 acc[8][4];
  gemm256(OutPre + (long)mb * 256 * DD, DD, Wot + (long)nb * 256 * DD, DD,
          DD / 64, lds, acc);
  const int t = threadIdx.x, lane = t & 63, w = t >> 6;
  const int wm = w >> 2, wn = w & 3, lr = lane & 15, lg = lane >> 4;
  int colbase = nb * 256 + wn * 64;
  float b4[4];
#pragma unroll
  for (int nf = 0; nf < 4; ++nf) b4[nf] = bo[colbase + nf * 16 + lr];
#pragma unroll
  for (int mf = 0; mf < 8; ++mf)
#pragma unroll
    for (int reg = 0; reg < 4; ++reg) {
      long row = mb * 256 + wm * 128 + mf * 16 + lg * 4 + reg;
#pragma unroll
      for (int nf = 0; nf < 4; ++nf)
        out[row * HID + colbase + nf * 16 + lr] = acc[mf][nf][reg] + b4[nf];
    }
}

extern "C" void kernel_launch(void* const* d_in, const int* in_sizes, int n_in,
                              void* d_out, int out_size, void* d_ws, size_t ws_size,
                              hipStream_t stream) {
  const float* hs = (const float*)d_in[0];
  const float* Wq = (const float*)d_in[1];
  const float* bq = (const float*)d_in[2];
  const float* Wk = (const float*)d_in[3];
  const float* bk = (const float*)d_in[4];
  const float* Wv = (const float*)d_in[5];
  const float* bv = (const float*)d_in[6];
  const float* Wg = (const float*)d_in[7];
  const float* bg = (const float*)d_in[8];
  const float* Wo = (const float*)d_in[9];
  const float* bo = (const float*)d_in[10];
  float* out = (float*)d_out;

  char* ws = (char*)d_ws;
  const size_t MB = 1024 * 1024;
  // P [2][4096][4096] bf16 (64MB) at 0; hsb (16MB) and Wt4 (16MB) alias its
  // start (dead before pair writes P). Wot at 64MB, QKVG at 68MB, Vt at 196MB.
  bf16_t* P = (bf16_t*)(ws);
  bf16_t* hsb = (bf16_t*)(ws);
  bf16_t* Wt4 = (bf16_t*)(ws + 16 * MB);
  bf16_t* Wot = (bf16_t*)(ws + 64 * MB);
  bf16_t* QKVG = (bf16_t*)(ws + 68 * MB);
  bf16_t* Vt = (bf16_t*)(ws + 196 * MB);

  bf16_t* Qb = QKVG;
  bf16_t* Kbuf = QKVG + (long)BS * DD;
  bf16_t* Vbuf = QKVG + 2l * BS * DD;
  bf16_t* Gbuf = QKVG + 3l * BS * DD;
  bf16_t* OutPre = Vbuf;  // V row-major dead after Vt built

  hipFuncSetAttribute((const void*)k_gemm_qkvg,
                      hipFuncAttributeMaxDynamicSharedMemorySize, LDS_BYTES);
  hipFuncSetAttribute((const void*)k_pair,
                      hipFuncAttributeMaxDynamicSharedMemorySize, LDS_BYTES);
  hipFuncSetAttribute((const void*)k_gemm2,
                      hipFuncAttributeMaxDynamicSharedMemorySize, LDS_BYTES);
  hipFuncSetAttribute((const void*)k_gemm3,
                      hipFuncAttributeMaxDynamicSharedMemorySize, LDS_BYTES);

  // 1. conversions
  k_cvt<<<(BS * HID / 4 + 255) / 256, 256, 0, stream>>>((const float4*)hs,
                                                        (bf16x4*)hsb, BS * HID / 4);
  k_tconv<<<dim3(DD / 64, HID / 64), 256, 0, stream>>>(Wq, Wt4 + 0l * DD * HID, HID, DD);
  k_tconv<<<dim3(DD / 64, HID / 64), 256, 0, stream>>>(Wk, Wt4 + 1l * DD * HID, HID, DD);
  k_tconv<<<dim3(DD / 64, HID / 64), 256, 0, stream>>>(Wv, Wt4 + 2l * DD * HID, HID, DD);
  k_tconv<<<dim3(DD / 64, HID / 64), 256, 0, stream>>>(Wg, Wt4 + 3l * DD * HID, HID, DD);
  k_tconv<<<dim3(HID / 64, DD / 64), 256, 0, stream>>>(Wo, Wot, DD, HID);

  // 2. QKVG projection (M=8192 x N=8192 x K=1024 over 256^2 tiles)
  k_gemm_qkvg<<<1024, 512, LDS_BYTES, stream>>>(hsb, Wt4, bq, bk, bv, bg, QKVG);

  // 3. V -> Vt [B][D][S]
  k_tbf16<<<dim3(DD / 64, SEQ / 64, NB_), 256, 0, stream>>>(Vbuf, Vt, SEQ, DD);

  // 4. pairwise scores + fused diag softmax (rect P, ld=4096)
  k_pair<<<dim3(136, 2), 512, LDS_BYTES, stream>>>(Qb, Kbuf, P);

  // 5. PV + gate (K=(m+1)*256, zero quadrant makes even-chunk rows exact)
  k_gemm2<<<dim3(8, 32), 512, LDS_BYTES, stream>>>(P, Vt, Gbuf, OutPre);

  // 6. output projection
  k_gemm3<<<128, 512, LDS_BYTES, stream>>>(OutPre, Wot, bo, out);
}

// Round 3
// 433.114 us; speedup vs baseline: 1.2429x; 1.1212x over previous
//
#include <hip/hip_runtime.h>
#include <hip/hip_bf16.h>
#include <math.h>

// ---------------------------------------------------------------------------
// ChunkGatedAttentionUnit: B=2, S=4096, H=1024, D=2048, CHUNK=128, nC=32
// Round 3: pipelined GEMM cores (2 counted-vmcnt sync points per K-tile,
// cross-phase ds_read prefetch), BM=128 variant for straggler-free pair /
// gemm2 (longest-first) / gemm3 grids. Diag softmax fused in pair.
// ---------------------------------------------------------------------------

typedef __bf16 bf16_t;
typedef __bf16 bf16x8 __attribute__((ext_vector_type(8)));
typedef __bf16 bf16x4 __attribute__((ext_vector_type(4)));
typedef float f32x4 __attribute__((ext_vector_type(4)));

#define NB_ 2
#define SEQ 4096
#define HID 1024
#define DD 2048
#define BS 8192
#define LDS256 131072
#define LDS128 98304

__device__ __forceinline__ void async16(const void* g, void* l) {
  __builtin_amdgcn_global_load_lds(
      (const __attribute__((address_space(1))) void*)g,
      (__attribute__((address_space(3))) void*)l, 16, 0, 0);
}

#define VMW(n) asm volatile("s_waitcnt vmcnt(" #n ")" ::: "memory")
#define BARR __builtin_amdgcn_s_barrier()
#define FEN asm volatile("" ::: "memory")

template <int MFH>
__device__ __forceinline__ void readA8(const bf16_t* bufA, int aBase, int s0, int s1,
                                       bf16x8 (&af)[4][2]) {
#pragma unroll
  for (int mm = 0; mm < 4; ++mm) {
    int p = aBase + MFH * 8192 + mm * 1024;
    af[mm][0] = *reinterpret_cast<const bf16x8*>(&bufA[p + s0]);
    af[mm][1] = *reinterpret_cast<const bf16x8*>(&bufA[p + s1]);
  }
}
template <int NFH>
__device__ __forceinline__ void readB4(const bf16_t* bufB, int bBase, int s0, int s1,
                                       bf16x8 (&bv)[2][2]) {
#pragma unroll
  for (int nn = 0; nn < 2; ++nn) {
    int p = bBase + NFH * 8192 + nn * 1024;
    bv[nn][0] = *reinterpret_cast<const bf16x8*>(&bufB[p + s0]);
    bv[nn][1] = *reinterpret_cast<const bf16x8*>(&bufB[p + s1]);
  }
}
template <int MROWS, int MQ, int NQ>
__device__ __forceinline__ void mfmaQ(const bf16x8 (&af)[4][2], const bf16x8 (&bv)[2][2],
                                      f32x4 (&acc)[MROWS][4]) {
  __builtin_amdgcn_s_setprio(1);
#pragma unroll
  for (int kki = 0; kki < 2; ++kki)
#pragma unroll
    for (int mm = 0; mm < 4; ++mm)
#pragma unroll
      for (int nn = 0; nn < 2; ++nn)
        acc[MQ * 4 + mm][NQ * 2 + nn] = __builtin_amdgcn_mfma_f32_16x16x32_bf16(
            af[mm][kki], bv[nn][kki], acc[MQ * 4 + mm][NQ * 2 + nn], 0, 0, 0);
  __builtin_amdgcn_s_setprio(0);
}

// ---- BM=256 x BN=256 core, BK=64, 8 waves (2Mx4N), per-wave 128x64 --------
// C = A[256,K] @ B[256,K]^T.  2 sync points / K-tile, counted vmcnt.
__device__ __forceinline__ void core256(const bf16_t* __restrict__ A, int lda,
                                        const bf16_t* __restrict__ B, int ldb, int nt,
                                        bf16_t* lds, f32x4 (&acc)[8][4]) {
  const int t = threadIdx.x;
  const int lane = t & 63, w = t >> 6;
  const int wm = w >> 2, wn = w & 3;
  const int lr = lane & 15, lg = lane >> 4;
  const int xm = lr & 7;
  const int aBase = (wm * 64 + lr) * 64;
  const int bBase = (wn * 32 + lr) * 64;
  const int s0 = (lg ^ xm) * 8, s1 = ((4 + lg) ^ xm) * 8;
  const int slog = ((t & 7) ^ ((t >> 3) & 7)) * 8;
  int srcA[4], srcB[4];
#pragma unroll
  for (int blk = 0; blk < 4; ++blk) {
    int rA = ((blk & 1) << 7) + ((blk >> 1) << 6) + (t >> 3);
    int prB = (blk << 6) + (t >> 3);
    int rB = (((prB >> 5) & 3) << 6) + ((prB >> 7) << 5) + (prB & 31);
    srcA[blk] = rA * lda + slog;
    srcB[blk] = rB * ldb + slog;
  }
  const int dstT = t * 8;
#pragma unroll
  for (int m = 0; m < 8; ++m)
#pragma unroll
    for (int n = 0; n < 4; ++n) acc[m][n] = (f32x4){0.f, 0.f, 0.f, 0.f};

  {  // prologue: stage tile 0; order A0,A1,B0,B1,A2,A3,B2,B3
    bf16_t* nA = lds;
    bf16_t* nB = lds + 16384;
    async16(A + srcA[0], nA + dstT);
    async16(A + srcA[1], nA + 4096 + dstT);
    async16(B + srcB[0], nB + dstT);
    async16(B + srcB[1], nB + 4096 + dstT);
    async16(A + srcA[2], nA + 8192 + dstT);
    async16(A + srcA[3], nA + 12288 + dstT);
    async16(B + srcB[2], nB + 8192 + dstT);
    async16(B + srcB[3], nB + 12288 + dstT);
  }
  bf16x8 af0[4][2], af1[4][2], bv0[2][2], bv1[2][2];
  for (int kt = 0; kt < nt; ++kt) {
    bf16_t* bufA = lds + ((kt & 1) << 15);
    bf16_t* bufB = bufA + 16384;
    bf16_t* nA = lds + (((kt + 1) & 1) << 15);
    bf16_t* nB = nA + 16384;
    const int kn = (kt + 1 < nt ? kt + 1 : 0) << 6;
    const bf16_t* An = A + kn;
    const bf16_t* Bn = B + kn;
    // p0: confirms A0,A1,B0,B1,A2,A3 (vmcnt(2)); reads af0,bv0,af1; MFMA q0
    VMW(2); BARR; FEN;
    readA8<0>(bufA, aBase, s0, s1, af0);
    readB4<0>(bufB, bBase, s0, s1, bv0);
    readA8<1>(bufA, aBase, s0, s1, af1);
    async16(An + srcA[0], nA + dstT);
    async16(An + srcA[1], nA + 4096 + dstT);
    mfmaQ<8, 0, 0>(af0, bv0, acc);
    // p1: confirms B2,B3 (vmcnt(2)); reads bv1; MFMA q1 (af1 prefetched)
    VMW(2); BARR; FEN;
    readB4<1>(bufB, bBase, s0, s1, bv1);
    async16(Bn + srcB[0], nB + dstT);
    async16(Bn + srcB[1], nB + 4096 + dstT);
    mfmaQ<8, 1, 0>(af1, bv0, acc);
    // p2: no sync; MFMA q2 (all regs)
    async16(An + srcA[2], nA + 8192 + dstT);
    async16(An + srcA[3], nA + 12288 + dstT);
    mfmaQ<8, 1, 1>(af1, bv1, acc);
    // p3: no sync; MFMA q3 (all regs)
    async16(Bn + srcB[2], nB + 8192 + dstT);
    async16(Bn + srcB[3], nB + 12288 + dstT);
    mfmaQ<8, 0, 1>(af0, bv1, acc);
  }
  VMW(0);
  BARR;
}

// ---- BM=128 x BN=256 core, BK=64, 8 waves (2Mx4N), per-wave 64x64 ---------
__device__ __forceinline__ void core128(const bf16_t* __restrict__ A, int lda,
                                        const bf16_t* __restrict__ B, int ldb, int nt,
                                        bf16_t* lds, f32x4 (&acc)[4][4]) {
  const int t = threadIdx.x;
  const int lane = t & 63, w = t >> 6;
  const int wm = w >> 2, wn = w & 3;  // wm 0..1 (64-row halves), wn 0..3
  const int lr = lane & 15, lg = lane >> 4;
  const int xm = lr & 7;
  const int aBase = (wm * 64 + lr) * 64;
  const int bBase = (wn * 32 + lr) * 64;
  const int s0 = (lg ^ xm) * 8, s1 = ((4 + lg) ^ xm) * 8;
  const int slog = ((t & 7) ^ ((t >> 3) & 7)) * 8;
  int srcA[2], srcB[4];
#pragma unroll
  for (int blk = 0; blk < 2; ++blk) srcA[blk] = (blk * 64 + (t >> 3)) * lda + slog;
#pragma unroll
  for (int blk = 0; blk < 4; ++blk) {
    int prB = (blk << 6) + (t >> 3);
    int rB = (((prB >> 5) & 3) << 6) + ((prB >> 7) << 5) + (prB & 31);
    srcB[blk] = rB * ldb + slog;
  }
  const int dstT = t * 8;
#pragma unroll
  for (int m = 0; m < 4; ++m)
#pragma unroll
    for (int n = 0; n < 4; ++n) acc[m][n] = (f32x4){0.f, 0.f, 0.f, 0.f};

  {  // prologue: order A0,A1,B0,B1,B2,B3
    bf16_t* nA = lds;
    bf16_t* nB = lds + 8192;
    async16(A + srcA[0], nA + dstT);
    async16(A + srcA[1], nA + 4096 + dstT);
    async16(B + srcB[0], nB + dstT);
    async16(B + srcB[1], nB + 4096 + dstT);
    async16(B + srcB[2], nB + 8192 + dstT);
    async16(B + srcB[3], nB + 12288 + dstT);
  }
  bf16x8 af[4][2], bv0[2][2], bv1[2][2];
  for (int kt = 0; kt < nt; ++kt) {
    bf16_t* bufA = lds + (kt & 1) * 24576;
    bf16_t* bufB = bufA + 8192;
    bf16_t* nA = lds + ((kt + 1) & 1) * 24576;
    bf16_t* nB = nA + 8192;
    const int kn = (kt + 1 < nt ? kt + 1 : 0) << 6;
    const bf16_t* An = A + kn;
    const bf16_t* Bn = B + kn;
    // p0: confirms A0,A1,B0,B1 (vmcnt(2)); reads af,bv0; MFMA q0
    VMW(2); BARR; FEN;
    readA8<0>(bufA, aBase, s0, s1, af);
    readB4<0>(bufB, bBase, s0, s1, bv0);
    async16(An + srcA[0], nA + dstT);
    async16(An + srcA[1], nA + 4096 + dstT);
    async16(Bn + srcB[0], nB + dstT);
    mfmaQ<4, 0, 0>(af, bv0, acc);
    // p1: confirms B2,B3 (vmcnt(3)); reads bv1; MFMA q1
    VMW(3); BARR; FEN;
    readB4<1>(bufB, bBase, s0, s1, bv1);
    async16(Bn + srcB[1], nB + 4096 + dstT);
    async16(Bn + srcB[2], nB + 8192 + dstT);
    async16(Bn + srcB[3], nB + 12288 + dstT);
    mfmaQ<4, 0, 1>(af, bv1, acc);
  }
  VMW(0);
  BARR;
}

// --- elementwise convert f32 -> bf16 ---------------------------------------
__global__ void k_cvt(const float4* __restrict__ in, bf16x4* __restrict__ out, int n4) {
  int i = blockIdx.x * blockDim.x + threadIdx.x;
  if (i < n4) {
    float4 v = in[i];
    bf16x4 o;
    o[0] = (bf16_t)v.x; o[1] = (bf16_t)v.y; o[2] = (bf16_t)v.z; o[3] = (bf16_t)v.w;
    out[i] = o;
  }
}

// --- tiled transpose + convert f32[R][C] -> bf16[C][R] ----------------------
__global__ void k_tconv(const float* __restrict__ in, bf16_t* __restrict__ out,
                        int R, int C) {
  __shared__ bf16_t tile[64][65];
  int bc = blockIdx.x, br = blockIdx.y;
  int t = threadIdx.x;
  int c = t & 63, r0 = t >> 6;
#pragma unroll
  for (int rr = 0; rr < 64; rr += 4) {
    int r = rr + r0;
    tile[r][c] = (bf16_t)in[(long)(br * 64 + r) * C + bc * 64 + c];
  }
  __syncthreads();
#pragma unroll
  for (int rr = 0; rr < 64; rr += 4) {
    int r = rr + r0;
    out[(long)(bc * 64 + r) * R + br * 64 + c] = tile[c][r];
  }
}

// --- tiled transpose bf16[R][C] -> bf16[C][R], per batch (z) ----------------
__global__ void k_tbf16(const bf16_t* __restrict__ in, bf16_t* __restrict__ out,
                        int R, int C) {
  __shared__ bf16_t tile[64][65];
  long zoff = (long)blockIdx.z * R * C;
  in += zoff;
  out += zoff;
  int bc = blockIdx.x, br = blockIdx.y;
  int t = threadIdx.x;
  int c = t & 63, r0 = t >> 6;
#pragma unroll
  for (int rr = 0; rr < 64; rr += 4) {
    int r = rr + r0;
    tile[r][c] = in[(long)(br * 64 + r) * C + bc * 64 + c];
  }
  __syncthreads();
#pragma unroll
  for (int rr = 0; rr < 64; rr += 4) {
    int r = rr + r0;
    out[(long)(bc * 64 + r) * R + br * 64 + c] = tile[c][r];
  }
}

// --- GEMM1: QKVG = hsb @ Wt^T + bias (sigmoid z==3), BM=256 ----------------
__global__ __launch_bounds__(512, 2) void k_gemm_qkvg(
    const bf16_t* __restrict__ hsb, const bf16_t* __restrict__ Wt4,
    const float* __restrict__ bq, const float* __restrict__ bk,
    const float* __restrict__ bv, const float* __restrict__ bg,
    bf16_t* __restrict__ out) {
  extern __shared__ bf16_t lds[];
  int c = blockIdx.x;
  int c2 = (c & 7) * 128 + (c >> 3);  // XCD swizzle (1024 % 8 == 0)
  int mb = c2 >> 5, nb = c2 & 31;
  f32x4 acc[8][4];
  core256(hsb + (long)mb * 256 * HID, HID, Wt4 + (long)nb * 256 * HID, HID,
          HID / 64, lds, acc);
  const int t = threadIdx.x, lane = t & 63, w = t >> 6;
  const int wm = w >> 2, wn = w & 3, lr = lane & 15, lg = lane >> 4;
  int z = nb >> 3;
  const float* bias = z == 0 ? bq : z == 1 ? bk : z == 2 ? bv : bg;
  int colbase = (nb & 7) * 256 + wn * 64;
  float b4[4];
#pragma unroll
  for (int nf = 0; nf < 4; ++nf) b4[nf] = bias[colbase + nf * 16 + lr];
  bf16_t* O = out + (long)z * BS * DD;
#pragma unroll
  for (int mf = 0; mf < 8; ++mf)
#pragma unroll
    for (int reg = 0; reg < 4; ++reg) {
      long row = mb * 256 + wm * 128 + mf * 16 + lg * 4 + reg;
#pragma unroll
      for (int nf = 0; nf < 4; ++nf) {
        float v = acc[mf][nf][reg] + b4[nf];
        if (z == 3) v = 1.f / (1.f + __expf(-v));
        O[row * DD + colbase + nf * 16 + lr] = (bf16_t)v;
      }
    }
}

// --- pair: P[row-chunk c][jt-tile] = Q K^T; fused diag softmax, BM=128 ------
__global__ __launch_bounds__(512, 2) void k_pair(const bf16_t* __restrict__ Q,
                                                 const bf16_t* __restrict__ Kb,
                                                 bf16_t* __restrict__ P) {
  extern __shared__ bf16_t lds[];
  int p = blockIdx.x, b = blockIdx.y;
  int c = 0, base = 0;
  while (base + (c >> 1) + 1 <= p) { base += (c >> 1) + 1; ++c; }
  int jt = p - base;  // jt in [0, (c>>1)]
  f32x4 acc[4][4];
  core128(Q + ((long)b * SEQ + (long)c * 128) * DD, DD,
          Kb + ((long)b * SEQ + (long)jt * 256) * DD, DD, DD / 64, lds, acc);
  const int t = threadIdx.x, lane = t & 63, w = t >> 6;
  const int wm = w >> 2, wn = w & 3, lr = lane & 15, lg = lane >> 4;
  bf16_t* Pt = P + ((long)b * SEQ + (long)c * 128) * (long)SEQ + (long)jt * 256;
  const bool hasDiag = (jt == (c >> 1));
  const int side = c & 1;
  const float scale = 0.02209708691207961f;  // 1/sqrt(2048)
  float* smf = (float*)lds;  // 64KB scratch; core quiesced LDS
#pragma unroll
  for (int mf = 0; mf < 4; ++mf)
#pragma unroll
    for (int reg = 0; reg < 4; ++reg) {
      int row = wm * 64 + mf * 16 + lg * 4 + reg;
#pragma unroll
      for (int nf = 0; nf < 4; ++nf) {
        int col = wn * 64 + nf * 16 + lr;
        float v = acc[mf][nf][reg];
        if (hasDiag && ((col >> 7) == side)) {
          int cc = col & 127;
          float sv = v * scale;
          smf[row * 128 + ((cc + row) & 127)] = (cc <= row) ? sv : -1e30f;
        } else {
          Pt[(long)row * SEQ + col] = (bf16_t)v;
        }
      }
    }
  if (hasDiag) {
    __syncthreads();
    if (t < 128) {
      int r = t;
      float mx = -1e30f;
      for (int cc = 0; cc <= r; ++cc) mx = fmaxf(mx, smf[r * 128 + ((cc + r) & 127)]);
      float s = 0.f;
      for (int cc = 0; cc <= r; ++cc) s += __expf(smf[r * 128 + ((cc + r) & 127)] - mx);
      float inv = 1.f / s;
      for (int cc = 0; cc < 128; ++cc) {
        float v = (cc <= r) ? __expf(smf[r * 128 + ((cc + r) & 127)] - mx) * inv : 0.f;
        Pt[(long)r * SEQ + side * 128 + cc] = (bf16_t)v;
      }
    }
  }
}

// --- GEMM2: OutPre = (P @ V[0:K]) * gate, BM=128, longest-first -------------
__global__ __launch_bounds__(512, 2) void k_gemm2(const bf16_t* __restrict__ P,
                                                  const bf16_t* __restrict__ Vt,
                                                  const bf16_t* __restrict__ G,
                                                  bf16_t* __restrict__ OutPre) {
  extern __shared__ bf16_t lds[];
  int bid = blockIdx.x;
  int mq = 31 - (bid >> 4);  // longest-first
  int r2 = bid & 15;
  int nb = r2 >> 1, b = r2 & 1;
  f32x4 acc[4][4];
  core128(P + ((long)b * SEQ + (long)mq * 128) * (long)SEQ, SEQ,
          Vt + (long)b * DD * SEQ + (long)nb * 256 * SEQ, SEQ, (mq + 1) * 2, lds, acc);
  const int t = threadIdx.x, lane = t & 63, w = t >> 6;
  const int wm = w >> 2, wn = w & 3, lr = lane & 15, lg = lane >> 4;
#pragma unroll
  for (int mf = 0; mf < 4; ++mf)
#pragma unroll
    for (int reg = 0; reg < 4; ++reg) {
      long row = (long)b * SEQ + (long)mq * 128 + wm * 64 + mf * 16 + lg * 4 + reg;
#pragma unroll
      for (int nf = 0; nf < 4; ++nf) {
        long idx = row * DD + nb * 256 + wn * 64 + nf * 16 + lr;
        float g = (float)G[idx];
        OutPre[idx] = (bf16_t)(acc[mf][nf][reg] * g);
      }
    }
}

// --- GEMM3: out = OutPre @ Wo + bo (f32 out), BM=128 ------------------------
__global__ __launch_bounds__(512, 2) void k_gemm3(const bf16_t* __restrict__ OutPre,
                                                  const bf16_t* __restrict__ Wot,
                                                  const float* __restrict__ bo,
                                                  float* __restrict__ out) {
  extern __shared__ bf16_t lds[];
  int mb = blockIdx.x >> 2, nb = blockIdx.x & 3;
  f32x4 acc[4][4];
  core128(OutPre + (long)mb * 128 * DD, DD, Wot + (long)nb * 256 * DD, DD,
          DD / 64, lds, acc);
  const int t = threadIdx.x, lane = t & 63, w = t >> 6;
  const int wm = w >> 2, wn = w & 3, lr = lane & 15, lg = lane >> 4;
  int colbase = nb * 256 + wn * 64;
  float b4[4];
#pragma unroll
  for (int nf = 0; nf < 4; ++nf) b4[nf] = bo[colbase + nf * 16 + lr];
#pragma unroll
  for (int mf = 0; mf < 4; ++mf)
#pragma unroll
    for (int reg = 0; reg < 4; ++reg) {
      long row = mb * 128 + wm * 64 + mf * 16 + lg * 4 + reg;
#pragma unroll
      for (int nf = 0; nf < 4; ++nf)
        out[row * HID + colbase + nf * 16 + lr] = acc[mf][nf][reg] + b4[nf];
    }
}

extern "C" void kernel_launch(void* const* d_in, const int* in_sizes, int n_in,
                              void* d_out, int out_size, void* d_ws, size_t ws_size,
                              hipStream_t stream) {
  const float* hs = (const float*)d_in[0];
  const float* Wq = (const float*)d_in[1];
  const float* bq = (const float*)d_in[2];
  const float* Wk = (const float*)d_in[3];
  const float* bk = (const float*)d_in[4];
  const float* Wv = (const float*)d_in[5];
  const float* bv = (const float*)d_in[6];
  const float* Wg = (const float*)d_in[7];
  const float* bg = (const float*)d_in[8];
  const float* Wo = (const float*)d_in[9];
  const float* bo = (const float*)d_in[10];
  float* out = (float*)d_out;

  char* ws = (char*)d_ws;
  const size_t MB = 1024 * 1024;
  // P [2][4096][4096] bf16 (64MB) at 0; hsb/Wt4 alias its start (dead before
  // pair writes P). Wot at 64MB, QKVG at 68MB, Vt at 196MB.
  bf16_t* P = (bf16_t*)(ws);
  bf16_t* hsb = (bf16_t*)(ws);
  bf16_t* Wt4 = (bf16_t*)(ws + 16 * MB);
  bf16_t* Wot = (bf16_t*)(ws + 64 * MB);
  bf16_t* QKVG = (bf16_t*)(ws + 68 * MB);
  bf16_t* Vt = (bf16_t*)(ws + 196 * MB);

  bf16_t* Qb = QKVG;
  bf16_t* Kbuf = QKVG + (long)BS * DD;
  bf16_t* Vbuf = QKVG + 2l * BS * DD;
  bf16_t* Gbuf = QKVG + 3l * BS * DD;
  bf16_t* OutPre = Vbuf;  // V row-major dead after Vt built

  hipFuncSetAttribute((const void*)k_gemm_qkvg,
                      hipFuncAttributeMaxDynamicSharedMemorySize, LDS256);
  hipFuncSetAttribute((const void*)k_pair,
                      hipFuncAttributeMaxDynamicSharedMemorySize, LDS128);
  hipFuncSetAttribute((const void*)k_gemm2,
                      hipFuncAttributeMaxDynamicSharedMemorySize, LDS128);
  hipFuncSetAttribute((const void*)k_gemm3,
                      hipFuncAttributeMaxDynamicSharedMemorySize, LDS128);

  // 1. conversions
  k_cvt<<<(BS * HID / 4 + 255) / 256, 256, 0, stream>>>((const float4*)hs,
                                                        (bf16x4*)hsb, BS * HID / 4);
  k_tconv<<<dim3(DD / 64, HID / 64), 256, 0, stream>>>(Wq, Wt4 + 0l * DD * HID, HID, DD);
  k_tconv<<<dim3(DD / 64, HID / 64), 256, 0, stream>>>(Wk, Wt4 + 1l * DD * HID, HID, DD);
  k_tconv<<<dim3(DD / 64, HID / 64), 256, 0, stream>>>(Wv, Wt4 + 2l * DD * HID, HID, DD);
  k_tconv<<<dim3(DD / 64, HID / 64), 256, 0, stream>>>(Wg, Wt4 + 3l * DD * HID, HID, DD);
  k_tconv<<<dim3(HID / 64, DD / 64), 256, 0, stream>>>(Wo, Wot, DD, HID);

  // 2. QKVG projection (8192 x 8192 x 1024, 256^2 tiles)
  k_gemm_qkvg<<<1024, 512, LDS256, stream>>>(hsb, Wt4, bq, bk, bv, bg, QKVG);

  // 3. V -> Vt [B][D][S]
  k_tbf16<<<dim3(DD / 64, SEQ / 64, NB_), 256, 0, stream>>>(Vbuf, Vt, SEQ, DD);

  // 4. pairwise scores + fused diag softmax (544 uniform 128x256 blocks)
  k_pair<<<dim3(272, 2), 512, LDS128, stream>>>(Qb, Kbuf, P);

  // 5. PV + gate (512 blocks, longest-first, K=(mq+1)*128)
  k_gemm2<<<512, 512, LDS128, stream>>>(P, Vt, Gbuf, OutPre);

  // 6. output projection (256 uniform blocks)
  k_gemm3<<<256, 512, LDS128, stream>>>(OutPre, Wot, bo, out);
}